// Round 1
// baseline (28036.102 us; speedup 1.0000x reference)
//
#include <hip/hip_runtime.h>
#include <math.h>

// ---------------------------------------------------------------------------
// AlexCapsNet (FOOD101) forward: AlexNet convs -> PrimaryCaps -> routing -> MLP
// Batch B=64 fixed by problem. All fp32.
// ---------------------------------------------------------------------------

#define BATCH 64

static inline int ceil_div(int a, int b) { return (a + b - 1) / b; }

// ---------------- direct conv, weights staged in LDS -----------------------
// block handles one (b, co, spatial-tile); thread per output pixel.
template<int K, int STRIDE, int PAD, bool RELU>
__global__ void conv_direct(const float* __restrict__ in, const float* __restrict__ wgt,
                            const float* __restrict__ bias, float* __restrict__ out,
                            int CIN, int COUT, int HIN, int WIN,
                            int HOUT, int WOUT, int tiles) {
    extern __shared__ float wsh[];
    int t  = blockIdx.x % tiles;
    int co = (blockIdx.x / tiles) % COUT;
    int b  = blockIdx.x / (tiles * COUT);
    const int WSZ = CIN * K * K;
    for (int idx = threadIdx.x; idx < WSZ; idx += blockDim.x)
        wsh[idx] = wgt[(size_t)co * WSZ + idx];
    __syncthreads();

    int pix = t * blockDim.x + threadIdx.x;
    if (pix >= HOUT * WOUT) return;
    int ho = pix / WOUT;
    int wo = pix - ho * WOUT;
    int hbase = ho * STRIDE - PAD;
    int wbase = wo * STRIDE - PAD;

    float acc = bias[co];
    const float* inb = in + (size_t)b * CIN * HIN * WIN;
    for (int ci = 0; ci < CIN; ci++) {
        const float* inc = inb + (size_t)ci * HIN * WIN;
        const float* wc  = wsh + ci * K * K;
#pragma unroll
        for (int kh = 0; kh < K; kh++) {
            int hi = hbase + kh;
            if (PAD > 0 && (hi < 0 || hi >= HIN)) continue;
            const float* rowp = inc + hi * WIN;
#pragma unroll
            for (int kw = 0; kw < K; kw++) {
                int wi = wbase + kw;
                if (PAD > 0 && (wi < 0 || wi >= WIN)) continue;
                acc = fmaf(rowp[wi], wc[kh * K + kw], acc);
            }
        }
    }
    if (RELU) acc = fmaxf(acc, 0.f);
    out[((size_t)(b * COUT + co) * HOUT + ho) * WOUT + wo] = acc;
}

// ---------------- maxpool (k x k, stride s, -inf padding) ------------------
__global__ void maxpool_k(const float* __restrict__ in, float* __restrict__ out,
                          int BC, int HIN, int WIN, int HOUT, int WOUT,
                          int KS, int S, int P) {
    int idx = blockIdx.x * blockDim.x + threadIdx.x;
    int total = BC * HOUT * WOUT;
    if (idx >= total) return;
    int wo = idx % WOUT;
    int ho = (idx / WOUT) % HOUT;
    int bc = idx / (WOUT * HOUT);
    int h0 = ho * S - P, w0 = wo * S - P;
    int h1 = h0 + KS, w1 = w0 + KS;
    if (h0 < 0) h0 = 0;
    if (w0 < 0) w0 = 0;
    if (h1 > HIN) h1 = HIN;
    if (w1 > WIN) w1 = WIN;
    const float* base = in + (size_t)bc * HIN * WIN;
    float m = -INFINITY;
    for (int h = h0; h < h1; h++)
        for (int w = w0; w < w1; w++)
            m = fmaxf(m, base[h * WIN + w]);
    out[idx] = m;
}

// ---------------- squash over trailing dim of 8 ----------------------------
__global__ void squash_u(const float* __restrict__ p, float* __restrict__ u, int ncaps) {
    int idx = blockIdx.x * blockDim.x + threadIdx.x;
    if (idx >= ncaps) return;
    const float4* pp = (const float4*)(p + (size_t)idx * 8);
    float4 a = pp[0], b = pp[1];
    float sq = a.x*a.x + a.y*a.y + a.z*a.z + a.w*a.w
             + b.x*b.x + b.y*b.y + b.z*b.z + b.w*b.w;
    float scale = (sq / (1.f + sq)) / sqrtf(sq + 1e-8f);
    float4* uu = (float4*)(u + (size_t)idx * 8);
    float4 oa, ob;
    oa.x = a.x*scale; oa.y = a.y*scale; oa.z = a.z*scale; oa.w = a.w*scale;
    ob.x = b.x*scale; ob.y = b.y*scale; ob.z = b.z*scale; ob.w = b.w*scale;
    uu[0] = oa; uu[1] = ob;
}

// ---------------- misc -----------------------------------------------------
__global__ void fill_zero(float* __restrict__ p, int n) {
    int idx = blockIdx.x * blockDim.x + threadIdx.x;
    if (idx < n) p[idx] = 0.f;
}

// ---------------- softmax over J (axis=1 of [B,J,I]) -----------------------
__global__ void softmax_j(const float* __restrict__ blog, float* __restrict__ c,
                          int Bn, int J, int I) {
    int idx = blockIdx.x * blockDim.x + threadIdx.x;
    if (idx >= Bn * I) return;
    int b = idx / I, i = idx - b * I;
    const float* base = blog + (size_t)b * J * I + i;
    float m = -INFINITY;
    for (int j = 0; j < J; j++) m = fmaxf(m, base[(size_t)j * I]);
    float* cb = c + (size_t)b * J * I + i;
    float sum = 0.f;
    for (int j = 0; j < J; j++) {
        float e = expf(base[(size_t)j * I] - m);
        sum += e;
        cb[(size_t)j * I] = e;
    }
    float inv = 1.f / sum;
    for (int j = 0; j < J; j++) cb[(size_t)j * I] *= inv;
}

// ---------------- routing: s[b,j,:] = sum_i c[b,j,i] * (W[j,i] @ u[b,i]) ---
// one block per (b,j); squash fused; writes v[b,j,0:16].
__global__ __launch_bounds__(256) void route_s(
        const float* __restrict__ c, const float* __restrict__ u,
        const float* __restrict__ W, float* __restrict__ v,
        int J, int I) {
    int bj = blockIdx.x;
    int b = bj / J, j = bj - b * J;
    int tid = threadIdx.x;

    float acc[16];
#pragma unroll
    for (int o = 0; o < 16; o++) acc[o] = 0.f;

    const float* cb = c + (size_t)bj * I;
    const float* ub = u + (size_t)b * I * 8;
    const float* Wj = W + (size_t)j * I * 128;

    for (int i = tid; i < I; i += 256) {
        float cc = cb[i];
        const float4* u4 = (const float4*)(ub + (size_t)i * 8);
        float4 ua = u4[0], ubv = u4[1];
        const float4* w4 = (const float4*)(Wj + (size_t)i * 128);
#pragma unroll
        for (int o = 0; o < 16; o++) {
            float4 wa = w4[2 * o], wb = w4[2 * o + 1];
            float dot = wa.x*ua.x + wa.y*ua.y + wa.z*ua.z + wa.w*ua.w
                      + wb.x*ubv.x + wb.y*ubv.y + wb.z*ubv.z + wb.w*ubv.w;
            acc[o] = fmaf(cc, dot, acc[o]);
        }
    }

    __shared__ float red[16][256];
#pragma unroll
    for (int o = 0; o < 16; o++) red[o][tid] = acc[o];
    __syncthreads();
    for (int off = 128; off > 0; off >>= 1) {
        if (tid < off) {
#pragma unroll
            for (int o = 0; o < 16; o++) red[o][tid] += red[o][tid + off];
        }
        __syncthreads();
    }
    if (tid == 0) {
        float sv[16];
        float ssq = 0.f;
#pragma unroll
        for (int o = 0; o < 16; o++) { sv[o] = red[o][0]; ssq += sv[o] * sv[o]; }
        float scale = (ssq / (1.f + ssq)) / sqrtf(ssq + 1e-8f);
#pragma unroll
        for (int o = 0; o < 16; o++) v[(size_t)bj * 16 + o] = sv[o] * scale;
    }
}

// ---------------- routing: b_logits += v . (W @ u) -------------------------
__global__ void route_bupd(const float* __restrict__ u, const float* __restrict__ W,
                           const float* __restrict__ v, float* __restrict__ blog,
                           int J, int I) {
    int idx = blockIdx.x * blockDim.x + threadIdx.x;
    int total = BATCH * J * I;
    if (idx >= total) return;
    int i = idx % I;
    int j = (idx / I) % J;
    int b = idx / (I * J);
    const float4* u4 = (const float4*)(u + ((size_t)b * I + i) * 8);
    float4 ua = u4[0], ub = u4[1];
    const float* vv = v + ((size_t)b * J + j) * 16;
    const float4* w4 = (const float4*)(W + ((size_t)j * I + i) * 128);
    float acc = 0.f;
#pragma unroll
    for (int o = 0; o < 16; o++) {
        float4 wa = w4[2 * o], wb = w4[2 * o + 1];
        float dot = wa.x*ua.x + wa.y*ua.y + wa.z*ua.z + wa.w*ua.w
                  + wb.x*ub.x + wb.y*ub.y + wb.z*ub.z + wb.w*ub.w;
        acc = fmaf(vv[o], dot, acc);
    }
    blog[idx] += acc;
}

// ---------------- fully-connected: out[m,n] = in[m,:] . w[n,:] + b ---------
template<bool RELU>
__global__ void fc_kernel(const float* __restrict__ in, const float* __restrict__ w,
                          const float* __restrict__ bias, float* __restrict__ out,
                          int M, int N, int K) {
    int idx = blockIdx.x * blockDim.x + threadIdx.x;
    if (idx >= M * N) return;
    int m = idx / N, n = idx - m * N;
    const float4* wr = (const float4*)(w + (size_t)n * K);
    const float4* xr = (const float4*)(in + (size_t)m * K);
    float acc = bias[n];
    int K4 = K >> 2;
    for (int k = 0; k < K4; k++) {
        float4 a = xr[k], bb = wr[k];
        acc = fmaf(a.x, bb.x, acc);
        acc = fmaf(a.y, bb.y, acc);
        acc = fmaf(a.z, bb.z, acc);
        acc = fmaf(a.w, bb.w, acc);
    }
    if (RELU) acc = fmaxf(acc, 0.f);
    out[idx] = acc;
}

// ---------------------------------------------------------------------------
extern "C" void kernel_launch(void* const* d_in, const int* in_sizes, int n_in,
                              void* d_out, int out_size, void* d_ws, size_t ws_size,
                              hipStream_t stream) {
    const float* x     = (const float*)d_in[0];
    const float* w1    = (const float*)d_in[1];
    const float* b1    = (const float*)d_in[2];
    const float* w2    = (const float*)d_in[3];
    const float* b2    = (const float*)d_in[4];
    const float* w3    = (const float*)d_in[5];
    const float* b3    = (const float*)d_in[6];
    const float* w4    = (const float*)d_in[7];
    const float* b4    = (const float*)d_in[8];
    const float* w5    = (const float*)d_in[9];
    const float* b5    = (const float*)d_in[10];
    const float* pc_w  = (const float*)d_in[11];
    const float* pc_b  = (const float*)d_in[12];
    const float* capsW = (const float*)d_in[13];
    const float* fc1_w = (const float*)d_in[14];
    const float* fc1_b = (const float*)d_in[15];
    const float* fc2_w = (const float*)d_in[16];
    const float* fc2_b = (const float*)d_in[17];
    const float* fc3_w = (const float*)d_in[18];
    const float* fc3_b = (const float*)d_in[19];
    float* outp = (float*)d_out;

    // workspace layout: A (80 MB) | B (20 MB) | D (4 MB)   -- total 104 MB
    char* ws = (char*)d_ws;
    float* A  = (float*)ws;                                  // big ping buffer
    float* Bb = (float*)(ws + ((size_t)80 << 20));           // pong buffer
    float* Dd = (float*)(ws + ((size_t)100 << 20));          // small tensors
    float* blog = A;                  // [64,101,1152]  (reuses A after convs)
    float* csm  = A + 7446528;        // [64,101,1152]
    float* vcap = Dd;                 // [64,101,16] = [64,1616]
    float* f1   = Dd + 131072;        // [64,4096]
    float* f2   = Dd + 131072 + 262144;

    const int B = BATCH;

    // ---- conv1: [64,3,227,227] -> [64,96,55,55], k11 s4 p0, relu ----
    {
        int tiles = ceil_div(55 * 55, 256);   // 12
        conv_direct<11, 4, 0, true><<<dim3(B * 96 * tiles), dim3(256),
            3 * 11 * 11 * sizeof(float), stream>>>(x, w1, b1, A, 3, 96, 227, 227, 55, 55, tiles);
    }
    // ---- pool1: -> [64,96,27,27] ----
    maxpool_k<<<dim3(ceil_div(B * 96 * 27 * 27, 256)), dim3(256), 0, stream>>>(
        A, Bb, B * 96, 55, 55, 27, 27, 3, 2, 0);
    // ---- conv2: -> [64,256,27,27], k5 s1 p2, relu ----
    {
        int tiles = ceil_div(27 * 27, 256);   // 3
        conv_direct<5, 1, 2, true><<<dim3(B * 256 * tiles), dim3(256),
            96 * 25 * sizeof(float), stream>>>(Bb, w2, b2, A, 96, 256, 27, 27, 27, 27, tiles);
    }
    // ---- pool2: -> [64,256,14,14] (k3 s2 p1) ----
    maxpool_k<<<dim3(ceil_div(B * 256 * 14 * 14, 256)), dim3(256), 0, stream>>>(
        A, Bb, B * 256, 27, 27, 14, 14, 3, 2, 1);
    // ---- conv3: -> [64,384,14,14] ----
    conv_direct<3, 1, 1, true><<<dim3(B * 384), dim3(256),
        256 * 9 * sizeof(float), stream>>>(Bb, w3, b3, A, 256, 384, 14, 14, 14, 14, 1);
    // ---- conv4: -> [64,384,14,14] ----
    conv_direct<3, 1, 1, true><<<dim3(B * 384), dim3(256),
        384 * 9 * sizeof(float), stream>>>(A, w4, b4, Bb, 384, 384, 14, 14, 14, 14, 1);
    // ---- conv5: -> [64,256,14,14] ----
    conv_direct<3, 1, 1, true><<<dim3(B * 256), dim3(256),
        384 * 9 * sizeof(float), stream>>>(Bb, w5, b5, A, 384, 256, 14, 14, 14, 14, 1);
    // ---- pool5: -> [64,256,6,6] ----
    maxpool_k<<<dim3(ceil_div(B * 256 * 6 * 6, 256)), dim3(256), 0, stream>>>(
        A, Bb, B * 256, 14, 14, 6, 6, 3, 2, 0);
    // ---- primarycaps conv: -> [64,256,6,6] (no relu) ----
    conv_direct<3, 1, 1, false><<<dim3(B * 256), dim3(64),
        256 * 9 * sizeof(float), stream>>>(Bb, pc_w, pc_b, A, 256, 256, 6, 6, 6, 6, 1);
    // ---- squash -> u [64,1152,8] ----
    squash_u<<<dim3(ceil_div(B * 1152, 256)), dim3(256), 0, stream>>>(A, Bb, B * 1152);

    // ---- dynamic routing (3 iters), x_hat recomputed on the fly ----
    fill_zero<<<dim3(ceil_div(B * 101 * 1152, 256)), dim3(256), 0, stream>>>(
        blog, B * 101 * 1152);
    for (int r = 0; r < 3; r++) {
        softmax_j<<<dim3(ceil_div(B * 1152, 256)), dim3(256), 0, stream>>>(
            blog, csm, B, 101, 1152);
        route_s<<<dim3(B * 101), dim3(256), 0, stream>>>(csm, Bb, capsW, vcap, 101, 1152);
        if (r < 2)
            route_bupd<<<dim3(ceil_div(B * 101 * 1152, 256)), dim3(256), 0, stream>>>(
                Bb, capsW, vcap, blog, 101, 1152);
    }

    // ---- MLP head ----
    fc_kernel<true><<<dim3(ceil_div(B * 4096, 256)), dim3(256), 0, stream>>>(
        vcap, fc1_w, fc1_b, f1, B, 4096, 1616);
    fc_kernel<true><<<dim3(ceil_div(B * 4096, 256)), dim3(256), 0, stream>>>(
        f1, fc2_w, fc2_b, f2, B, 4096, 4096);
    fc_kernel<false><<<dim3(ceil_div(B * 101, 256)), dim3(256), 0, stream>>>(
        f2, fc3_w, fc3_b, outp, B, 101, 4096);
}

// Round 2
// 13559.325 us; speedup vs baseline: 2.0677x; 2.0677x over previous
//
#include <hip/hip_runtime.h>
#include <math.h>

// ---------------------------------------------------------------------------
// AlexCapsNet (FOOD101) forward. Round 2: implicit-GEMM convs + tiled FC GEMM.
// Batch B=64 fixed. All fp32.
// ---------------------------------------------------------------------------

#define BATCH 64

static inline int ceil_div(int a, int b) { return (a + b - 1) / b; }

// ---------------------------------------------------------------------------
// Implicit-GEMM conv: C[cout, pix] = W[cout, cin*K*K] x im2col[cin*K*K, pix]
// Block tile: 64 couts x 64 pixels, K-chunk 32. Thread: 4 couts x 4 pixels.
// LDS rows padded to 68 floats (16B-aligned, conflict-light).
// ---------------------------------------------------------------------------
template<int K, int STRIDE, int PAD, int WOUT, bool RELU>
__global__ __launch_bounds__(256, 4) void conv_igemm(
        const float* __restrict__ in, const float* __restrict__ wgt,
        const float* __restrict__ bias, float* __restrict__ out,
        int CIN, int COUT, int HIN, int WIN, int HOUT) {
    constexpr int KC  = 32;
    constexpr int LDA = 68;
    __shared__ float Ash[KC * LDA];   // [kk][cout]
    __shared__ float Bsh[KC * LDA];   // [kk][pixel]

    const int npix = HOUT * WOUT;
    const int Ktot = CIN * K * K;

    const int tid = threadIdx.x;
    const int px0 = blockIdx.x * 64;
    const int co0 = blockIdx.y * 64;
    const int b   = blockIdx.z;

    const int tc = tid & 15;    // cout sub-tile 0..15
    const int tp = tid >> 4;    // pixel sub-tile 0..15

    float acc[4][4] = {{0.f}};

    const float* inb = in + (size_t)b * CIN * HIN * WIN;

    for (int k0 = 0; k0 < Ktot; k0 += KC) {
        // ---- stage A (weights): 64 couts x 32 k, float4 global reads ----
#pragma unroll
        for (int it = 0; it < 2; ++it) {
            int idx = tid + it * 256;        // 0..511
            int co  = idx >> 3;              // 0..63
            int k4  = idx & 7;
            int k   = k0 + k4 * 4;
            float4 w4 = make_float4(0.f, 0.f, 0.f, 0.f);
            int cog = co0 + co;
            if (cog < COUT) {
                const float* wp = wgt + (size_t)cog * Ktot + k;
                if (k + 3 < Ktot) {
                    w4 = *(const float4*)wp;
                } else {
                    if (k + 0 < Ktot) w4.x = wp[0];
                    if (k + 1 < Ktot) w4.y = wp[1];
                    if (k + 2 < Ktot) w4.z = wp[2];
                    if (k + 3 < Ktot) w4.w = wp[3];
                }
            }
            Ash[(k4 * 4 + 0) * LDA + co] = w4.x;
            Ash[(k4 * 4 + 1) * LDA + co] = w4.y;
            Ash[(k4 * 4 + 2) * LDA + co] = w4.z;
            Ash[(k4 * 4 + 3) * LDA + co] = w4.w;
        }
        // ---- stage B (im2col gather): 32 k x 64 px ----
#pragma unroll
        for (int it = 0; it < 8; ++it) {
            int idx = tid + it * 256;        // 0..2047
            int px  = idx & 63;
            int kk  = idx >> 6;
            int k   = k0 + kk;
            float v = 0.f;
            int p = px0 + px;
            if (k < Ktot && p < npix) {
                int ci = k / (K * K);
                int r  = k - ci * K * K;
                int kh = r / K;
                int kw = r - kh * K;
                int ho = p / WOUT;
                int wo = p - ho * WOUT;
                int hi = ho * STRIDE - PAD + kh;
                int wi = wo * STRIDE - PAD + kw;
                if (hi >= 0 && hi < HIN && wi >= 0 && wi < WIN)
                    v = inb[((size_t)ci * HIN + hi) * WIN + wi];
            }
            Bsh[kk * LDA + px] = v;
        }
        __syncthreads();
        // ---- inner product over the chunk ----
#pragma unroll
        for (int kk = 0; kk < KC; ++kk) {
            float4 a4 = *(const float4*)&Ash[kk * LDA + tc * 4];
            float4 b4 = *(const float4*)&Bsh[kk * LDA + tp * 4];
            float av[4] = {a4.x, a4.y, a4.z, a4.w};
            float bv[4] = {b4.x, b4.y, b4.z, b4.w};
#pragma unroll
            for (int i = 0; i < 4; ++i)
#pragma unroll
                for (int j = 0; j < 4; ++j)
                    acc[i][j] = fmaf(av[i], bv[j], acc[i][j]);
        }
        __syncthreads();
    }

    // ---- epilogue: bias + relu + store ----
#pragma unroll
    for (int i = 0; i < 4; ++i) {
        int cog = co0 + tc * 4 + i;
        if (cog >= COUT) continue;
        float bs = bias[cog];
        float* ob = out + (size_t)(b * COUT + cog) * npix;
#pragma unroll
        for (int j = 0; j < 4; ++j) {
            int p = px0 + tp * 4 + j;
            if (p >= npix) continue;
            float vv = acc[i][j] + bs;
            if (RELU) vv = fmaxf(vv, 0.f);
            ob[p] = vv;
        }
    }
}

// ---------------------------------------------------------------------------
// FC GEMM: out[m,n] = in[m,:] . w[n,:] + bias[n].  Tile 64n x 64m, chunk 32.
// ---------------------------------------------------------------------------
template<bool RELU>
__global__ __launch_bounds__(256, 4) void fc_gemm(
        const float* __restrict__ in, const float* __restrict__ w,
        const float* __restrict__ bias, float* __restrict__ out,
        int M, int N, int Kd) {
    constexpr int KC  = 32;
    constexpr int LDA = 68;
    __shared__ float Ash[KC * LDA];   // [kk][n]
    __shared__ float Bsh[KC * LDA];   // [kk][m]

    const int tid = threadIdx.x;
    const int n0 = blockIdx.x * 64;

    const int tn = tid & 15;
    const int tm = tid >> 4;

    float acc[4][4] = {{0.f}};

    for (int k0 = 0; k0 < Kd; k0 += KC) {
#pragma unroll
        for (int it = 0; it < 2; ++it) {
            int idx = tid + it * 256;
            int n   = idx >> 3;
            int k4  = idx & 7;
            int k   = k0 + k4 * 4;
            float4 w4 = make_float4(0.f, 0.f, 0.f, 0.f);
            int ng = n0 + n;
            if (ng < N) {
                const float* wp = w + (size_t)ng * Kd + k;
                if (k + 3 < Kd) {
                    w4 = *(const float4*)wp;
                } else {
                    if (k + 0 < Kd) w4.x = wp[0];
                    if (k + 1 < Kd) w4.y = wp[1];
                    if (k + 2 < Kd) w4.z = wp[2];
                    if (k + 3 < Kd) w4.w = wp[3];
                }
            }
            Ash[(k4 * 4 + 0) * LDA + n] = w4.x;
            Ash[(k4 * 4 + 1) * LDA + n] = w4.y;
            Ash[(k4 * 4 + 2) * LDA + n] = w4.z;
            Ash[(k4 * 4 + 3) * LDA + n] = w4.w;
        }
#pragma unroll
        for (int it = 0; it < 2; ++it) {
            int idx = tid + it * 256;
            int m   = idx >> 3;
            int k4  = idx & 7;
            int k   = k0 + k4 * 4;
            float4 x4 = make_float4(0.f, 0.f, 0.f, 0.f);
            if (m < M) {
                const float* xp = in + (size_t)m * Kd + k;
                if (k + 3 < Kd) {
                    x4 = *(const float4*)xp;
                } else {
                    if (k + 0 < Kd) x4.x = xp[0];
                    if (k + 1 < Kd) x4.y = xp[1];
                    if (k + 2 < Kd) x4.z = xp[2];
                    if (k + 3 < Kd) x4.w = xp[3];
                }
            }
            Bsh[(k4 * 4 + 0) * LDA + m] = x4.x;
            Bsh[(k4 * 4 + 1) * LDA + m] = x4.y;
            Bsh[(k4 * 4 + 2) * LDA + m] = x4.z;
            Bsh[(k4 * 4 + 3) * LDA + m] = x4.w;
        }
        __syncthreads();
#pragma unroll
        for (int kk = 0; kk < KC; ++kk) {
            float4 a4 = *(const float4*)&Ash[kk * LDA + tn * 4];
            float4 b4 = *(const float4*)&Bsh[kk * LDA + tm * 4];
            float av[4] = {a4.x, a4.y, a4.z, a4.w};
            float bv[4] = {b4.x, b4.y, b4.z, b4.w};
#pragma unroll
            for (int i = 0; i < 4; ++i)
#pragma unroll
                for (int j = 0; j < 4; ++j)
                    acc[i][j] = fmaf(av[i], bv[j], acc[i][j]);
        }
        __syncthreads();
    }

#pragma unroll
    for (int i = 0; i < 4; ++i) {
        int ng = n0 + tn * 4 + i;
        if (ng >= N) continue;
        float bs = bias[ng];
#pragma unroll
        for (int j = 0; j < 4; ++j) {
            int m = tm * 4 + j;
            if (m >= M) continue;
            float vv = acc[i][j] + bs;
            if (RELU) vv = fmaxf(vv, 0.f);
            out[(size_t)m * N + ng] = vv;
        }
    }
}

// ---------------- maxpool (k x k, stride s, -inf padding) ------------------
__global__ void maxpool_k(const float* __restrict__ in, float* __restrict__ out,
                          int BC, int HIN, int WIN, int HOUT, int WOUT,
                          int KS, int S, int P) {
    int idx = blockIdx.x * blockDim.x + threadIdx.x;
    int total = BC * HOUT * WOUT;
    if (idx >= total) return;
    int wo = idx % WOUT;
    int ho = (idx / WOUT) % HOUT;
    int bc = idx / (WOUT * HOUT);
    int h0 = ho * S - P, w0 = wo * S - P;
    int h1 = h0 + KS, w1 = w0 + KS;
    if (h0 < 0) h0 = 0;
    if (w0 < 0) w0 = 0;
    if (h1 > HIN) h1 = HIN;
    if (w1 > WIN) w1 = WIN;
    const float* base = in + (size_t)bc * HIN * WIN;
    float m = -INFINITY;
    for (int h = h0; h < h1; h++)
        for (int w = w0; w < w1; w++)
            m = fmaxf(m, base[h * WIN + w]);
    out[idx] = m;
}

// ---------------- squash over trailing dim of 8 ----------------------------
__global__ void squash_u(const float* __restrict__ p, float* __restrict__ u, int ncaps) {
    int idx = blockIdx.x * blockDim.x + threadIdx.x;
    if (idx >= ncaps) return;
    const float4* pp = (const float4*)(p + (size_t)idx * 8);
    float4 a = pp[0], b = pp[1];
    float sq = a.x*a.x + a.y*a.y + a.z*a.z + a.w*a.w
             + b.x*b.x + b.y*b.y + b.z*b.z + b.w*b.w;
    float scale = (sq / (1.f + sq)) / sqrtf(sq + 1e-8f);
    float4* uu = (float4*)(u + (size_t)idx * 8);
    float4 oa, ob;
    oa.x = a.x*scale; oa.y = a.y*scale; oa.z = a.z*scale; oa.w = a.w*scale;
    ob.x = b.x*scale; ob.y = b.y*scale; ob.z = b.z*scale; ob.w = b.w*scale;
    uu[0] = oa; uu[1] = ob;
}

// ---------------- softmax over J (axis=1 of [B,J,I]) -----------------------
__global__ void softmax_j(const float* __restrict__ blog, float* __restrict__ c,
                          int Bn, int J, int I) {
    int idx = blockIdx.x * blockDim.x + threadIdx.x;
    if (idx >= Bn * I) return;
    int b = idx / I, i = idx - b * I;
    const float* base = blog + (size_t)b * J * I + i;
    float m = -INFINITY;
    for (int j = 0; j < J; j++) m = fmaxf(m, base[(size_t)j * I]);
    float* cb = c + (size_t)b * J * I + i;
    float sum = 0.f;
    for (int j = 0; j < J; j++) {
        float e = expf(base[(size_t)j * I] - m);
        sum += e;
        cb[(size_t)j * I] = e;
    }
    float inv = 1.f / sum;
    for (int j = 0; j < J; j++) cb[(size_t)j * I] *= inv;
}

// ---------------- routing: s[b,j,:] = sum_i c[b,j,i] * (W[j,i] @ u[b,i]) ---
// one block per (b,j); squash fused; writes v[b,j,0:16].
// uniform != 0 -> c == 1/J (softmax of zero logits), skip reading c.
__global__ __launch_bounds__(256) void route_s(
        const float* __restrict__ c, const float* __restrict__ u,
        const float* __restrict__ W, float* __restrict__ v,
        int J, int I, int uniform) {
    int bj = blockIdx.x;
    int b = bj / J;
    int tid = threadIdx.x;
    const float invJ = 1.f / (float)J;

    float acc[16];
#pragma unroll
    for (int o = 0; o < 16; o++) acc[o] = 0.f;

    const float* cb = c + (size_t)bj * I;
    const float* ub = u + (size_t)b * I * 8;
    int j = bj - b * J;
    const float* Wj = W + (size_t)j * I * 128;

    for (int i = tid; i < I; i += 256) {
        float cc = uniform ? invJ : cb[i];
        const float4* u4 = (const float4*)(ub + (size_t)i * 8);
        float4 ua = u4[0], ubv = u4[1];
        const float4* w4 = (const float4*)(Wj + (size_t)i * 128);
#pragma unroll
        for (int o = 0; o < 16; o++) {
            float4 wa = w4[2 * o], wb = w4[2 * o + 1];
            float dot = wa.x*ua.x + wa.y*ua.y + wa.z*ua.z + wa.w*ua.w
                      + wb.x*ubv.x + wb.y*ubv.y + wb.z*ubv.z + wb.w*ubv.w;
            acc[o] = fmaf(cc, dot, acc[o]);
        }
    }

    __shared__ float red[16][256];
#pragma unroll
    for (int o = 0; o < 16; o++) red[o][tid] = acc[o];
    __syncthreads();
    for (int off = 128; off > 0; off >>= 1) {
        if (tid < off) {
#pragma unroll
            for (int o = 0; o < 16; o++) red[o][tid] += red[o][tid + off];
        }
        __syncthreads();
    }
    if (tid == 0) {
        float sv[16];
        float ssq = 0.f;
#pragma unroll
        for (int o = 0; o < 16; o++) { sv[o] = red[o][0]; ssq += sv[o] * sv[o]; }
        float scale = (ssq / (1.f + ssq)) / sqrtf(ssq + 1e-8f);
#pragma unroll
        for (int o = 0; o < 16; o++) v[(size_t)bj * 16 + o] = sv[o] * scale;
    }
}

// ---------------- routing: b_logits (+)= v . (W @ u) -----------------------
__global__ void route_bupd(const float* __restrict__ u, const float* __restrict__ W,
                           const float* __restrict__ v, float* __restrict__ blog,
                           int J, int I, int accumulate) {
    int idx = blockIdx.x * blockDim.x + threadIdx.x;
    int total = BATCH * J * I;
    if (idx >= total) return;
    int i = idx % I;
    int j = (idx / I) % J;
    int b = idx / (I * J);
    const float4* u4 = (const float4*)(u + ((size_t)b * I + i) * 8);
    float4 ua = u4[0], ub = u4[1];
    const float* vv = v + ((size_t)b * J + j) * 16;
    const float4* w4 = (const float4*)(W + ((size_t)j * I + i) * 128);
    float acc = 0.f;
#pragma unroll
    for (int o = 0; o < 16; o++) {
        float4 wa = w4[2 * o], wb = w4[2 * o + 1];
        float dot = wa.x*ua.x + wa.y*ua.y + wa.z*ua.z + wa.w*ua.w
                  + wb.x*ub.x + wb.y*ub.y + wb.z*ub.z + wb.w*ub.w;
        acc = fmaf(vv[o], dot, acc);
    }
    blog[idx] = accumulate ? (blog[idx] + acc) : acc;
}

// ---------------------------------------------------------------------------
extern "C" void kernel_launch(void* const* d_in, const int* in_sizes, int n_in,
                              void* d_out, int out_size, void* d_ws, size_t ws_size,
                              hipStream_t stream) {
    const float* x     = (const float*)d_in[0];
    const float* w1    = (const float*)d_in[1];
    const float* b1    = (const float*)d_in[2];
    const float* w2    = (const float*)d_in[3];
    const float* b2    = (const float*)d_in[4];
    const float* w3    = (const float*)d_in[5];
    const float* b3    = (const float*)d_in[6];
    const float* w4    = (const float*)d_in[7];
    const float* b4    = (const float*)d_in[8];
    const float* w5    = (const float*)d_in[9];
    const float* b5    = (const float*)d_in[10];
    const float* pc_w  = (const float*)d_in[11];
    const float* pc_b  = (const float*)d_in[12];
    const float* capsW = (const float*)d_in[13];
    const float* fc1_w = (const float*)d_in[14];
    const float* fc1_b = (const float*)d_in[15];
    const float* fc2_w = (const float*)d_in[16];
    const float* fc2_b = (const float*)d_in[17];
    const float* fc3_w = (const float*)d_in[18];
    const float* fc3_b = (const float*)d_in[19];
    float* outp = (float*)d_out;

    // workspace layout: A (80 MB) | B (20 MB) | D (4 MB)   -- total 104 MB
    char* ws = (char*)d_ws;
    float* A  = (float*)ws;
    float* Bb = (float*)(ws + ((size_t)80 << 20));
    float* Dd = (float*)(ws + ((size_t)100 << 20));
    float* blog = A;                  // [64,101,1152] (reuses A after convs)
    float* csm  = A + 7446528;        // [64,101,1152]
    float* vcap = Dd;                 // [64,101,16]
    float* f1   = Dd + 131072;        // [64,4096]
    float* f2   = Dd + 131072 + 262144;

    const int B = BATCH;

    // ---- conv1: [64,3,227,227] -> [64,96,55,55], k11 s4 p0, relu ----
    conv_igemm<11, 4, 0, 55, true><<<dim3(48, 2, B), dim3(256), 0, stream>>>(
        x, w1, b1, A, 3, 96, 227, 227, 55);
    // ---- pool1: -> [64,96,27,27] ----
    maxpool_k<<<dim3(ceil_div(B * 96 * 27 * 27, 256)), dim3(256), 0, stream>>>(
        A, Bb, B * 96, 55, 55, 27, 27, 3, 2, 0);
    // ---- conv2: -> [64,256,27,27], k5 s1 p2, relu ----
    conv_igemm<5, 1, 2, 27, true><<<dim3(12, 4, B), dim3(256), 0, stream>>>(
        Bb, w2, b2, A, 96, 256, 27, 27, 27);
    // ---- pool2: -> [64,256,14,14] (k3 s2 p1) ----
    maxpool_k<<<dim3(ceil_div(B * 256 * 14 * 14, 256)), dim3(256), 0, stream>>>(
        A, Bb, B * 256, 27, 27, 14, 14, 3, 2, 1);
    // ---- conv3: -> [64,384,14,14] ----
    conv_igemm<3, 1, 1, 14, true><<<dim3(4, 6, B), dim3(256), 0, stream>>>(
        Bb, w3, b3, A, 256, 384, 14, 14, 14);
    // ---- conv4: -> [64,384,14,14] ----
    conv_igemm<3, 1, 1, 14, true><<<dim3(4, 6, B), dim3(256), 0, stream>>>(
        A, w4, b4, Bb, 384, 384, 14, 14, 14);
    // ---- conv5: -> [64,256,14,14] ----
    conv_igemm<3, 1, 1, 14, true><<<dim3(4, 4, B), dim3(256), 0, stream>>>(
        Bb, w5, b5, A, 384, 256, 14, 14, 14);
    // ---- pool5: -> [64,256,6,6] ----
    maxpool_k<<<dim3(ceil_div(B * 256 * 6 * 6, 256)), dim3(256), 0, stream>>>(
        A, Bb, B * 256, 14, 14, 6, 6, 3, 2, 0);
    // ---- primarycaps conv: -> [64,256,6,6] (no relu) ----
    conv_igemm<3, 1, 1, 6, false><<<dim3(1, 4, B), dim3(256), 0, stream>>>(
        Bb, pc_w, pc_b, A, 256, 256, 6, 6, 6);
    // ---- squash -> u [64,1152,8] ----
    squash_u<<<dim3(ceil_div(B * 1152, 256)), dim3(256), 0, stream>>>(A, Bb, B * 1152);

    // ---- dynamic routing (3 iters), x_hat recomputed on the fly ----
    // r=0: c is uniform (softmax of zeros); first bupd writes (no init needed)
    route_s<<<dim3(B * 101), dim3(256), 0, stream>>>(csm, Bb, capsW, vcap, 101, 1152, 1);
    route_bupd<<<dim3(ceil_div(B * 101 * 1152, 256)), dim3(256), 0, stream>>>(
        Bb, capsW, vcap, blog, 101, 1152, 0);
    // r=1
    softmax_j<<<dim3(ceil_div(B * 1152, 256)), dim3(256), 0, stream>>>(
        blog, csm, B, 101, 1152);
    route_s<<<dim3(B * 101), dim3(256), 0, stream>>>(csm, Bb, capsW, vcap, 101, 1152, 0);
    route_bupd<<<dim3(ceil_div(B * 101 * 1152, 256)), dim3(256), 0, stream>>>(
        Bb, capsW, vcap, blog, 101, 1152, 1);
    // r=2 (final)
    softmax_j<<<dim3(ceil_div(B * 1152, 256)), dim3(256), 0, stream>>>(
        blog, csm, B, 101, 1152);
    route_s<<<dim3(B * 101), dim3(256), 0, stream>>>(csm, Bb, capsW, vcap, 101, 1152, 0);

    // ---- MLP head ----
    fc_gemm<true><<<dim3(64), dim3(256), 0, stream>>>(vcap, fc1_w, fc1_b, f1, B, 4096, 1616);
    fc_gemm<true><<<dim3(64), dim3(256), 0, stream>>>(f1, fc2_w, fc2_b, f2, B, 4096, 4096);
    fc_gemm<false><<<dim3(2), dim3(256), 0, stream>>>(f2, fc3_w, fc3_b, outp, B, 101, 4096);
}

// Round 3
// 13534.610 us; speedup vs baseline: 2.0714x; 1.0018x over previous
//
#include <hip/hip_runtime.h>
#include <math.h>

// ---------------------------------------------------------------------------
// AlexCapsNet (FOOD101) forward. Round 3: x_hat-materialized routing
// (caps_W read once, amortized over batch) + round-2 implicit-GEMM convs.
// Batch B=64 fixed. All fp32.
// ---------------------------------------------------------------------------

#define BATCH 64
#define NJ 101
#define NI 1152

static inline int ceil_div(int a, int b) { return (a + b - 1) / b; }

// ---------------------------------------------------------------------------
// Implicit-GEMM conv: C[cout, pix] = W[cout, cin*K*K] x im2col[cin*K*K, pix]
// Block tile: 64 couts x 64 pixels, K-chunk 32. Thread: 4 couts x 4 pixels.
// ---------------------------------------------------------------------------
template<int K, int STRIDE, int PAD, int WOUT, bool RELU>
__global__ __launch_bounds__(256, 4) void conv_igemm(
        const float* __restrict__ in, const float* __restrict__ wgt,
        const float* __restrict__ bias, float* __restrict__ out,
        int CIN, int COUT, int HIN, int WIN, int HOUT) {
    constexpr int KC  = 32;
    constexpr int LDA = 68;
    __shared__ float Ash[KC * LDA];   // [kk][cout]
    __shared__ float Bsh[KC * LDA];   // [kk][pixel]

    const int npix = HOUT * WOUT;
    const int Ktot = CIN * K * K;

    const int tid = threadIdx.x;
    const int px0 = blockIdx.x * 64;
    const int co0 = blockIdx.y * 64;
    const int b   = blockIdx.z;

    const int tc = tid & 15;
    const int tp = tid >> 4;

    float acc[4][4] = {{0.f}};

    const float* inb = in + (size_t)b * CIN * HIN * WIN;

    for (int k0 = 0; k0 < Ktot; k0 += KC) {
#pragma unroll
        for (int it = 0; it < 2; ++it) {
            int idx = tid + it * 256;
            int co  = idx >> 3;
            int k4  = idx & 7;
            int k   = k0 + k4 * 4;
            float4 w4 = make_float4(0.f, 0.f, 0.f, 0.f);
            int cog = co0 + co;
            if (cog < COUT) {
                const float* wp = wgt + (size_t)cog * Ktot + k;
                if (k + 3 < Ktot) {
                    w4 = *(const float4*)wp;
                } else {
                    if (k + 0 < Ktot) w4.x = wp[0];
                    if (k + 1 < Ktot) w4.y = wp[1];
                    if (k + 2 < Ktot) w4.z = wp[2];
                    if (k + 3 < Ktot) w4.w = wp[3];
                }
            }
            Ash[(k4 * 4 + 0) * LDA + co] = w4.x;
            Ash[(k4 * 4 + 1) * LDA + co] = w4.y;
            Ash[(k4 * 4 + 2) * LDA + co] = w4.z;
            Ash[(k4 * 4 + 3) * LDA + co] = w4.w;
        }
#pragma unroll
        for (int it = 0; it < 8; ++it) {
            int idx = tid + it * 256;
            int px  = idx & 63;
            int kk  = idx >> 6;
            int k   = k0 + kk;
            float v = 0.f;
            int p = px0 + px;
            if (k < Ktot && p < npix) {
                int ci = k / (K * K);
                int r  = k - ci * K * K;
                int kh = r / K;
                int kw = r - kh * K;
                int ho = p / WOUT;
                int wo = p - ho * WOUT;
                int hi = ho * STRIDE - PAD + kh;
                int wi = wo * STRIDE - PAD + kw;
                if (hi >= 0 && hi < HIN && wi >= 0 && wi < WIN)
                    v = inb[((size_t)ci * HIN + hi) * WIN + wi];
            }
            Bsh[kk * LDA + px] = v;
        }
        __syncthreads();
#pragma unroll
        for (int kk = 0; kk < KC; ++kk) {
            float4 a4 = *(const float4*)&Ash[kk * LDA + tc * 4];
            float4 b4 = *(const float4*)&Bsh[kk * LDA + tp * 4];
            float av[4] = {a4.x, a4.y, a4.z, a4.w};
            float bv[4] = {b4.x, b4.y, b4.z, b4.w};
#pragma unroll
            for (int i = 0; i < 4; ++i)
#pragma unroll
                for (int j = 0; j < 4; ++j)
                    acc[i][j] = fmaf(av[i], bv[j], acc[i][j]);
        }
        __syncthreads();
    }

#pragma unroll
    for (int i = 0; i < 4; ++i) {
        int cog = co0 + tc * 4 + i;
        if (cog >= COUT) continue;
        float bs = bias[cog];
        float* ob = out + (size_t)(b * COUT + cog) * npix;
#pragma unroll
        for (int j = 0; j < 4; ++j) {
            int p = px0 + tp * 4 + j;
            if (p >= npix) continue;
            float vv = acc[i][j] + bs;
            if (RELU) vv = fmaxf(vv, 0.f);
            ob[p] = vv;
        }
    }
}

// ---------------------------------------------------------------------------
// FC GEMM: out[m,n] = in[m,:] . w[n,:] + bias[n].  Tile 64n x 64m, chunk 32.
// ---------------------------------------------------------------------------
template<bool RELU>
__global__ __launch_bounds__(256, 4) void fc_gemm(
        const float* __restrict__ in, const float* __restrict__ w,
        const float* __restrict__ bias, float* __restrict__ out,
        int M, int N, int Kd) {
    constexpr int KC  = 32;
    constexpr int LDA = 68;
    __shared__ float Ash[KC * LDA];
    __shared__ float Bsh[KC * LDA];

    const int tid = threadIdx.x;
    const int n0 = blockIdx.x * 64;

    const int tn = tid & 15;
    const int tm = tid >> 4;

    float acc[4][4] = {{0.f}};

    for (int k0 = 0; k0 < Kd; k0 += KC) {
#pragma unroll
        for (int it = 0; it < 2; ++it) {
            int idx = tid + it * 256;
            int n   = idx >> 3;
            int k4  = idx & 7;
            int k   = k0 + k4 * 4;
            float4 w4 = make_float4(0.f, 0.f, 0.f, 0.f);
            int ng = n0 + n;
            if (ng < N) {
                const float* wp = w + (size_t)ng * Kd + k;
                if (k + 3 < Kd) {
                    w4 = *(const float4*)wp;
                } else {
                    if (k + 0 < Kd) w4.x = wp[0];
                    if (k + 1 < Kd) w4.y = wp[1];
                    if (k + 2 < Kd) w4.z = wp[2];
                    if (k + 3 < Kd) w4.w = wp[3];
                }
            }
            Ash[(k4 * 4 + 0) * LDA + n] = w4.x;
            Ash[(k4 * 4 + 1) * LDA + n] = w4.y;
            Ash[(k4 * 4 + 2) * LDA + n] = w4.z;
            Ash[(k4 * 4 + 3) * LDA + n] = w4.w;
        }
#pragma unroll
        for (int it = 0; it < 2; ++it) {
            int idx = tid + it * 256;
            int m   = idx >> 3;
            int k4  = idx & 7;
            int k   = k0 + k4 * 4;
            float4 x4 = make_float4(0.f, 0.f, 0.f, 0.f);
            if (m < M) {
                const float* xp = in + (size_t)m * Kd + k;
                if (k + 3 < Kd) {
                    x4 = *(const float4*)xp;
                } else {
                    if (k + 0 < Kd) x4.x = xp[0];
                    if (k + 1 < Kd) x4.y = xp[1];
                    if (k + 2 < Kd) x4.z = xp[2];
                    if (k + 3 < Kd) x4.w = xp[3];
                }
            }
            Bsh[(k4 * 4 + 0) * LDA + m] = x4.x;
            Bsh[(k4 * 4 + 1) * LDA + m] = x4.y;
            Bsh[(k4 * 4 + 2) * LDA + m] = x4.z;
            Bsh[(k4 * 4 + 3) * LDA + m] = x4.w;
        }
        __syncthreads();
#pragma unroll
        for (int kk = 0; kk < KC; ++kk) {
            float4 a4 = *(const float4*)&Ash[kk * LDA + tn * 4];
            float4 b4 = *(const float4*)&Bsh[kk * LDA + tm * 4];
            float av[4] = {a4.x, a4.y, a4.z, a4.w};
            float bv[4] = {b4.x, b4.y, b4.z, b4.w};
#pragma unroll
            for (int i = 0; i < 4; ++i)
#pragma unroll
                for (int j = 0; j < 4; ++j)
                    acc[i][j] = fmaf(av[i], bv[j], acc[i][j]);
        }
        __syncthreads();
    }

#pragma unroll
    for (int i = 0; i < 4; ++i) {
        int ng = n0 + tn * 4 + i;
        if (ng >= N) continue;
        float bs = bias[ng];
#pragma unroll
        for (int j = 0; j < 4; ++j) {
            int m = tm * 4 + j;
            if (m >= M) continue;
            float vv = acc[i][j] + bs;
            if (RELU) vv = fmaxf(vv, 0.f);
            out[(size_t)m * N + ng] = vv;
        }
    }
}

// ---------------- maxpool ---------------------------------------------------
__global__ void maxpool_k(const float* __restrict__ in, float* __restrict__ out,
                          int BC, int HIN, int WIN, int HOUT, int WOUT,
                          int KS, int S, int P) {
    int idx = blockIdx.x * blockDim.x + threadIdx.x;
    int total = BC * HOUT * WOUT;
    if (idx >= total) return;
    int wo = idx % WOUT;
    int ho = (idx / WOUT) % HOUT;
    int bc = idx / (WOUT * HOUT);
    int h0 = ho * S - P, w0 = wo * S - P;
    int h1 = h0 + KS, w1 = w0 + KS;
    if (h0 < 0) h0 = 0;
    if (w0 < 0) w0 = 0;
    if (h1 > HIN) h1 = HIN;
    if (w1 > WIN) w1 = WIN;
    const float* base = in + (size_t)bc * HIN * WIN;
    float m = -INFINITY;
    for (int h = h0; h < h1; h++)
        for (int w = w0; w < w1; w++)
            m = fmaxf(m, base[h * WIN + w]);
    out[idx] = m;
}

// ---------------- squash over trailing dim of 8 ----------------------------
__global__ void squash_u(const float* __restrict__ p, float* __restrict__ u, int ncaps) {
    int idx = blockIdx.x * blockDim.x + threadIdx.x;
    if (idx >= ncaps) return;
    const float4* pp = (const float4*)(p + (size_t)idx * 8);
    float4 a = pp[0], b = pp[1];
    float sq = a.x*a.x + a.y*a.y + a.z*a.z + a.w*a.w
             + b.x*b.x + b.y*b.y + b.z*b.z + b.w*b.w;
    float scale = (sq / (1.f + sq)) / sqrtf(sq + 1e-8f);
    float4* uu = (float4*)(u + (size_t)idx * 8);
    float4 oa, ob;
    oa.x = a.x*scale; oa.y = a.y*scale; oa.z = a.z*scale; oa.w = a.w*scale;
    ob.x = b.x*scale; ob.y = b.y*scale; ob.z = b.z*scale; ob.w = b.w*scale;
    uu[0] = oa; uu[1] = ob;
}

// ---------------- softmax over J (axis=1 of [B,J,I]) -----------------------
__global__ void softmax_j(const float* __restrict__ blog, float* __restrict__ c,
                          int Bn, int J, int I) {
    int idx = blockIdx.x * blockDim.x + threadIdx.x;
    if (idx >= Bn * I) return;
    int b = idx / I, i = idx - b * I;
    const float* base = blog + (size_t)b * J * I + i;
    float m = -INFINITY;
    for (int j = 0; j < J; j++) m = fmaxf(m, base[(size_t)j * I]);
    float* cb = c + (size_t)b * J * I + i;
    float sum = 0.f;
    for (int j = 0; j < J; j++) {
        float e = expf(base[(size_t)j * I] - m);
        sum += e;
        cb[(size_t)j * I] = e;
    }
    float inv = 1.f / sum;
    for (int j = 0; j < J; j++) cb[(size_t)j * I] *= inv;
}

// ===========================================================================
// FAST routing path: x_hat materialized once. Layout xh[b][j][i][o], o fastest.
// ===========================================================================

// x_hat[b,j,i,:] = W[j,i] (16x8) @ u[b,i] (8). W fragment held in regs,
// looped over all 64 b -> W read exactly once from HBM.
__global__ __launch_bounds__(256) void xhat_compute(
        const float* __restrict__ u, const float* __restrict__ W,
        float* __restrict__ xh) {
    int gid = blockIdx.x * 256 + threadIdx.x;   // 2*NJ*NI threads exactly
    int og = gid & 1;                           // half of o-range (8 o's)
    int rest = gid >> 1;                        // j*NI + i
    int i = rest % NI;
    int j = rest / NI;

    const float4* Wp = (const float4*)(W + (size_t)rest * 128 + og * 64);
    float4 w[16];
#pragma unroll
    for (int t = 0; t < 16; t++) w[t] = Wp[t];

    for (int b = 0; b < BATCH; b++) {
        const float4* up = (const float4*)(u + ((size_t)b * NI + i) * 8);
        float4 ua = up[0], ub = up[1];
        float acc[8];
#pragma unroll
        for (int oo = 0; oo < 8; oo++) {
            float4 wa = w[2 * oo], wb = w[2 * oo + 1];
            acc[oo] = wa.x*ua.x + wa.y*ua.y + wa.z*ua.z + wa.w*ua.w
                    + wb.x*ub.x + wb.y*ub.y + wb.z*ub.z + wb.w*ub.w;
        }
        float4* op = (float4*)(xh + (((size_t)(b * NJ + j) * NI + i) * 16) + og * 8);
        op[0] = make_float4(acc[0], acc[1], acc[2], acc[3]);
        op[1] = make_float4(acc[4], acc[5], acc[6], acc[7]);
    }
}

// s[b,j,o] = sum_i c[b,j,i] * xh[b,j,i,o]; squash -> v[b,j,o].
// One 64-thread block per (b,j): thread = (o in 16, iq in 4).
__global__ __launch_bounds__(64) void route_sv(
        const float* __restrict__ c, const float* __restrict__ xh,
        float* __restrict__ v, int uniform) {
    int bj = blockIdx.x;
    int tid = threadIdx.x;
    int o  = tid & 15;
    int iq = tid >> 4;
    const float invJ = 1.f / (float)NJ;

    const float* xb = xh + (size_t)bj * NI * 16;
    const float* cb = c + (size_t)bj * NI;

    float s0 = 0.f, s1 = 0.f, s2 = 0.f, s3 = 0.f;
    int i0 = iq * (NI / 4), i1 = i0 + (NI / 4);
    for (int ii = i0; ii < i1; ii += 4) {
        float4 c4;
        if (uniform) c4 = make_float4(invJ, invJ, invJ, invJ);
        else         c4 = *(const float4*)&cb[ii];
        s0 = fmaf(c4.x, xb[(size_t)(ii + 0) * 16 + o], s0);
        s1 = fmaf(c4.y, xb[(size_t)(ii + 1) * 16 + o], s1);
        s2 = fmaf(c4.z, xb[(size_t)(ii + 2) * 16 + o], s2);
        s3 = fmaf(c4.w, xb[(size_t)(ii + 3) * 16 + o], s3);
    }
    float s = (s0 + s1) + (s2 + s3);

    __shared__ float red[4][16];
    __shared__ float sarr[16];
    red[iq][o] = s;
    __syncthreads();
    if (tid < 16) sarr[tid] = red[0][tid] + red[1][tid] + red[2][tid] + red[3][tid];
    __syncthreads();
    if (tid < 16) {
        float ssq = 0.f;
#pragma unroll
        for (int k = 0; k < 16; k++) ssq += sarr[k] * sarr[k];
        float scale = (ssq / (1.f + ssq)) / sqrtf(ssq + 1e-8f);
        v[(size_t)bj * 16 + tid] = sarr[tid] * scale;
    }
}

// blog[b,j,i] (+)= sum_o v[b,j,o] * xh[b,j,i,o]
__global__ __launch_bounds__(256) void route_bupd2(
        const float* __restrict__ xh, const float* __restrict__ v,
        float* __restrict__ blog, int accumulate) {
    int idx = blockIdx.x * 256 + threadIdx.x;    // BATCH*NJ*NI exactly
    int i  = idx % NI;
    int bj = idx / NI;
    const float4* xp = (const float4*)(xh + ((size_t)bj * NI + i) * 16);
    const float4* vp = (const float4*)(v + (size_t)bj * 16);
    float4 v0 = vp[0], v1 = vp[1], v2 = vp[2], v3 = vp[3];
    float4 x0 = xp[0], x1 = xp[1], x2 = xp[2], x3 = xp[3];
    float d = v0.x*x0.x + v0.y*x0.y + v0.z*x0.z + v0.w*x0.w
            + v1.x*x1.x + v1.y*x1.y + v1.z*x1.z + v1.w*x1.w
            + v2.x*x2.x + v2.y*x2.y + v2.z*x2.z + v2.w*x2.w
            + v3.x*x3.x + v3.y*x3.y + v3.z*x3.z + v3.w*x3.w;
    blog[idx] = accumulate ? (blog[idx] + d) : d;
}

// ===========================================================================
// FALLBACK routing (round-2 kernels, used when ws_size too small for x_hat)
// ===========================================================================
__global__ __launch_bounds__(256) void route_s(
        const float* __restrict__ c, const float* __restrict__ u,
        const float* __restrict__ W, float* __restrict__ v,
        int J, int I, int uniform) {
    int bj = blockIdx.x;
    int b = bj / J;
    int tid = threadIdx.x;
    const float invJ = 1.f / (float)J;

    float acc[16];
#pragma unroll
    for (int o = 0; o < 16; o++) acc[o] = 0.f;

    const float* cb = c + (size_t)bj * I;
    const float* ub = u + (size_t)b * I * 8;
    int j = bj - b * J;
    const float* Wj = W + (size_t)j * I * 128;

    for (int i = tid; i < I; i += 256) {
        float cc = uniform ? invJ : cb[i];
        const float4* u4 = (const float4*)(ub + (size_t)i * 8);
        float4 ua = u4[0], ubv = u4[1];
        const float4* w4 = (const float4*)(Wj + (size_t)i * 128);
#pragma unroll
        for (int o = 0; o < 16; o++) {
            float4 wa = w4[2 * o], wb = w4[2 * o + 1];
            float dot = wa.x*ua.x + wa.y*ua.y + wa.z*ua.z + wa.w*ua.w
                      + wb.x*ubv.x + wb.y*ubv.y + wb.z*ubv.z + wb.w*ubv.w;
            acc[o] = fmaf(cc, dot, acc[o]);
        }
    }

    __shared__ float red[16][256];
#pragma unroll
    for (int o = 0; o < 16; o++) red[o][tid] = acc[o];
    __syncthreads();
    for (int off = 128; off > 0; off >>= 1) {
        if (tid < off) {
#pragma unroll
            for (int o = 0; o < 16; o++) red[o][tid] += red[o][tid + off];
        }
        __syncthreads();
    }
    if (tid == 0) {
        float sv[16];
        float ssq = 0.f;
#pragma unroll
        for (int o = 0; o < 16; o++) { sv[o] = red[o][0]; ssq += sv[o] * sv[o]; }
        float scale = (ssq / (1.f + ssq)) / sqrtf(ssq + 1e-8f);
#pragma unroll
        for (int o = 0; o < 16; o++) v[(size_t)bj * 16 + o] = sv[o] * scale;
    }
}

__global__ void route_bupd(const float* __restrict__ u, const float* __restrict__ W,
                           const float* __restrict__ v, float* __restrict__ blog,
                           int J, int I, int accumulate) {
    int idx = blockIdx.x * blockDim.x + threadIdx.x;
    int total = BATCH * J * I;
    if (idx >= total) return;
    int i = idx % I;
    int j = (idx / I) % J;
    int b = idx / (I * J);
    const float4* u4 = (const float4*)(u + ((size_t)b * I + i) * 8);
    float4 ua = u4[0], ub = u4[1];
    const float* vv = v + ((size_t)b * J + j) * 16;
    const float4* w4 = (const float4*)(W + ((size_t)j * I + i) * 128);
    float acc = 0.f;
#pragma unroll
    for (int o = 0; o < 16; o++) {
        float4 wa = w4[2 * o], wb = w4[2 * o + 1];
        float dot = wa.x*ua.x + wa.y*ua.y + wa.z*ua.z + wa.w*ua.w
                  + wb.x*ub.x + wb.y*ub.y + wb.z*ub.z + wb.w*ub.w;
        acc = fmaf(vv[o], dot, acc);
    }
    blog[idx] = accumulate ? (blog[idx] + acc) : acc;
}

// ---------------------------------------------------------------------------
extern "C" void kernel_launch(void* const* d_in, const int* in_sizes, int n_in,
                              void* d_out, int out_size, void* d_ws, size_t ws_size,
                              hipStream_t stream) {
    const float* x     = (const float*)d_in[0];
    const float* w1    = (const float*)d_in[1];
    const float* b1    = (const float*)d_in[2];
    const float* w2    = (const float*)d_in[3];
    const float* b2    = (const float*)d_in[4];
    const float* w3    = (const float*)d_in[5];
    const float* b3    = (const float*)d_in[6];
    const float* w4    = (const float*)d_in[7];
    const float* b4    = (const float*)d_in[8];
    const float* w5    = (const float*)d_in[9];
    const float* b5    = (const float*)d_in[10];
    const float* pc_w  = (const float*)d_in[11];
    const float* pc_b  = (const float*)d_in[12];
    const float* capsW = (const float*)d_in[13];
    const float* fc1_w = (const float*)d_in[14];
    const float* fc1_b = (const float*)d_in[15];
    const float* fc2_w = (const float*)d_in[16];
    const float* fc2_b = (const float*)d_in[17];
    const float* fc3_w = (const float*)d_in[18];
    const float* fc3_b = (const float*)d_in[19];
    float* outp = (float*)d_out;

    // ws layout: A (80 MB) | Bb (20 MB) | Dd (4 MB) | xh (476.6 MB, fast path)
    char* ws = (char*)d_ws;
    float* A  = (float*)ws;
    float* Bb = (float*)(ws + ((size_t)80 << 20));
    float* Dd = (float*)(ws + ((size_t)100 << 20));
    float* xh = (float*)(ws + ((size_t)104 << 20));
    float* blog = A;                  // [64,101,1152] (A free after convs)
    float* csm  = A + 7446528;        // [64,101,1152]
    float* vcap = Dd;                 // [64,101,16]
    float* f1   = Dd + 131072;
    float* f2   = Dd + 131072 + 262144;

    const size_t XH_BYTES = (size_t)BATCH * NJ * NI * 16 * sizeof(float); // 476.6 MB
    const bool fast = ws_size >= ((size_t)104 << 20) + XH_BYTES;

    const int B = BATCH;
    const int BJI = B * NJ * NI;

    // ---- conv stack (unchanged from round 2) ----
    conv_igemm<11, 4, 0, 55, true><<<dim3(48, 2, B), dim3(256), 0, stream>>>(
        x, w1, b1, A, 3, 96, 227, 227, 55);
    maxpool_k<<<dim3(ceil_div(B * 96 * 27 * 27, 256)), dim3(256), 0, stream>>>(
        A, Bb, B * 96, 55, 55, 27, 27, 3, 2, 0);
    conv_igemm<5, 1, 2, 27, true><<<dim3(12, 4, B), dim3(256), 0, stream>>>(
        Bb, w2, b2, A, 96, 256, 27, 27, 27);
    maxpool_k<<<dim3(ceil_div(B * 256 * 14 * 14, 256)), dim3(256), 0, stream>>>(
        A, Bb, B * 256, 27, 27, 14, 14, 3, 2, 1);
    conv_igemm<3, 1, 1, 14, true><<<dim3(4, 6, B), dim3(256), 0, stream>>>(
        Bb, w3, b3, A, 256, 384, 14, 14, 14);
    conv_igemm<3, 1, 1, 14, true><<<dim3(4, 6, B), dim3(256), 0, stream>>>(
        A, w4, b4, Bb, 384, 384, 14, 14, 14);
    conv_igemm<3, 1, 1, 14, true><<<dim3(4, 4, B), dim3(256), 0, stream>>>(
        Bb, w5, b5, A, 384, 256, 14, 14, 14);
    maxpool_k<<<dim3(ceil_div(B * 256 * 6 * 6, 256)), dim3(256), 0, stream>>>(
        A, Bb, B * 256, 14, 14, 6, 6, 3, 2, 0);
    conv_igemm<3, 1, 1, 6, false><<<dim3(1, 4, B), dim3(256), 0, stream>>>(
        Bb, pc_w, pc_b, A, 256, 256, 6, 6, 6);
    squash_u<<<dim3(ceil_div(B * 1152, 256)), dim3(256), 0, stream>>>(A, Bb, B * 1152);
    // u now lives in Bb [64,1152,8]

    if (fast) {
        // ---- x_hat once; W read exactly once ----
        xhat_compute<<<dim3(2 * NJ * NI / 256), dim3(256), 0, stream>>>(Bb, capsW, xh);
        // r=0 (uniform c)
        route_sv<<<dim3(B * NJ), dim3(64), 0, stream>>>(csm, xh, vcap, 1);
        route_bupd2<<<dim3(BJI / 256), dim3(256), 0, stream>>>(xh, vcap, blog, 0);
        // r=1
        softmax_j<<<dim3(ceil_div(B * NI, 256)), dim3(256), 0, stream>>>(
            blog, csm, B, NJ, NI);
        route_sv<<<dim3(B * NJ), dim3(64), 0, stream>>>(csm, xh, vcap, 0);
        route_bupd2<<<dim3(BJI / 256), dim3(256), 0, stream>>>(xh, vcap, blog, 1);
        // r=2 (final)
        softmax_j<<<dim3(ceil_div(B * NI, 256)), dim3(256), 0, stream>>>(
            blog, csm, B, NJ, NI);
        route_sv<<<dim3(B * NJ), dim3(64), 0, stream>>>(csm, xh, vcap, 0);
    } else {
        route_s<<<dim3(B * NJ), dim3(256), 0, stream>>>(csm, Bb, capsW, vcap, NJ, NI, 1);
        route_bupd<<<dim3(ceil_div(BJI, 256)), dim3(256), 0, stream>>>(
            Bb, capsW, vcap, blog, NJ, NI, 0);
        softmax_j<<<dim3(ceil_div(B * NI, 256)), dim3(256), 0, stream>>>(
            blog, csm, B, NJ, NI);
        route_s<<<dim3(B * NJ), dim3(256), 0, stream>>>(csm, Bb, capsW, vcap, NJ, NI, 0);
        route_bupd<<<dim3(ceil_div(BJI, 256)), dim3(256), 0, stream>>>(
            Bb, capsW, vcap, blog, NJ, NI, 1);
        softmax_j<<<dim3(ceil_div(B * NI, 256)), dim3(256), 0, stream>>>(
            blog, csm, B, NJ, NI);
        route_s<<<dim3(B * NJ), dim3(256), 0, stream>>>(csm, Bb, capsW, vcap, NJ, NI, 0);
    }

    // ---- MLP head ----
    fc_gemm<true><<<dim3(64), dim3(256), 0, stream>>>(vcap, fc1_w, fc1_b, f1, B, 4096, 1616);
    fc_gemm<true><<<dim3(64), dim3(256), 0, stream>>>(f1, fc2_w, fc2_b, f2, B, 4096, 4096);
    fc_gemm<false><<<dim3(2), dim3(256), 0, stream>>>(f2, fc3_w, fc3_b, outp, B, 101, 4096);
}

// Round 4
// 5859.797 us; speedup vs baseline: 4.7845x; 2.3097x over previous
//
#include <hip/hip_runtime.h>
#include <math.h>

// ---------------------------------------------------------------------------
// AlexCapsNet (FOOD101) forward. Round 4: LDS-staged W routing (W read once
// per kernel, amortized over batch inside the block; no x_hat buffer).
// Batch B=64 fixed. All fp32.
// ---------------------------------------------------------------------------

#define BATCH 64
#define NJ 101
#define NI 1152
#define BJ (BATCH * NJ)          // 6464
#define IC 64                    // i-chunk per block
#define NIC (NI / IC)            // 18
#define LDW 132                  // padded LDS row stride (words), 16B-aligned

static inline int ceil_div(int a, int b) { return (a + b - 1) / b; }

// ---------------------------------------------------------------------------
// Implicit-GEMM conv: C[cout, pix] = W[cout, cin*K*K] x im2col[cin*K*K, pix]
// Block tile: 64 couts x 64 pixels, K-chunk 32. Thread: 4 couts x 4 pixels.
// ---------------------------------------------------------------------------
template<int K, int STRIDE, int PAD, int WOUT, bool RELU>
__global__ __launch_bounds__(256, 4) void conv_igemm(
        const float* __restrict__ in, const float* __restrict__ wgt,
        const float* __restrict__ bias, float* __restrict__ out,
        int CIN, int COUT, int HIN, int WIN, int HOUT) {
    constexpr int KC  = 32;
    constexpr int LDA = 68;
    __shared__ float Ash[KC * LDA];   // [kk][cout]
    __shared__ float Bsh[KC * LDA];   // [kk][pixel]

    const int npix = HOUT * WOUT;
    const int Ktot = CIN * K * K;

    const int tid = threadIdx.x;
    const int px0 = blockIdx.x * 64;
    const int co0 = blockIdx.y * 64;
    const int b   = blockIdx.z;

    const int tc = tid & 15;
    const int tp = tid >> 4;

    float acc[4][4] = {{0.f}};

    const float* inb = in + (size_t)b * CIN * HIN * WIN;

    for (int k0 = 0; k0 < Ktot; k0 += KC) {
#pragma unroll
        for (int it = 0; it < 2; ++it) {
            int idx = tid + it * 256;
            int co  = idx >> 3;
            int k4  = idx & 7;
            int k   = k0 + k4 * 4;
            float4 w4 = make_float4(0.f, 0.f, 0.f, 0.f);
            int cog = co0 + co;
            if (cog < COUT) {
                const float* wp = wgt + (size_t)cog * Ktot + k;
                if (k + 3 < Ktot) {
                    w4 = *(const float4*)wp;
                } else {
                    if (k + 0 < Ktot) w4.x = wp[0];
                    if (k + 1 < Ktot) w4.y = wp[1];
                    if (k + 2 < Ktot) w4.z = wp[2];
                    if (k + 3 < Ktot) w4.w = wp[3];
                }
            }
            Ash[(k4 * 4 + 0) * LDA + co] = w4.x;
            Ash[(k4 * 4 + 1) * LDA + co] = w4.y;
            Ash[(k4 * 4 + 2) * LDA + co] = w4.z;
            Ash[(k4 * 4 + 3) * LDA + co] = w4.w;
        }
#pragma unroll
        for (int it = 0; it < 8; ++it) {
            int idx = tid + it * 256;
            int px  = idx & 63;
            int kk  = idx >> 6;
            int k   = k0 + kk;
            float v = 0.f;
            int p = px0 + px;
            if (k < Ktot && p < npix) {
                int ci = k / (K * K);
                int r  = k - ci * K * K;
                int kh = r / K;
                int kw = r - kh * K;
                int ho = p / WOUT;
                int wo = p - ho * WOUT;
                int hi = ho * STRIDE - PAD + kh;
                int wi = wo * STRIDE - PAD + kw;
                if (hi >= 0 && hi < HIN && wi >= 0 && wi < WIN)
                    v = inb[((size_t)ci * HIN + hi) * WIN + wi];
            }
            Bsh[kk * LDA + px] = v;
        }
        __syncthreads();
#pragma unroll
        for (int kk = 0; kk < KC; ++kk) {
            float4 a4 = *(const float4*)&Ash[kk * LDA + tc * 4];
            float4 b4 = *(const float4*)&Bsh[kk * LDA + tp * 4];
            float av[4] = {a4.x, a4.y, a4.z, a4.w};
            float bv[4] = {b4.x, b4.y, b4.z, b4.w};
#pragma unroll
            for (int i = 0; i < 4; ++i)
#pragma unroll
                for (int j = 0; j < 4; ++j)
                    acc[i][j] = fmaf(av[i], bv[j], acc[i][j]);
        }
        __syncthreads();
    }

#pragma unroll
    for (int i = 0; i < 4; ++i) {
        int cog = co0 + tc * 4 + i;
        if (cog >= COUT) continue;
        float bs = bias[cog];
        float* ob = out + (size_t)(b * COUT + cog) * npix;
#pragma unroll
        for (int j = 0; j < 4; ++j) {
            int p = px0 + tp * 4 + j;
            if (p >= npix) continue;
            float vv = acc[i][j] + bs;
            if (RELU) vv = fmaxf(vv, 0.f);
            ob[p] = vv;
        }
    }
}

// ---------------------------------------------------------------------------
// FC GEMM: out[m,n] = in[m,:] . w[n,:] + bias[n].  Tile 64n x 64m, chunk 32.
// ---------------------------------------------------------------------------
template<bool RELU>
__global__ __launch_bounds__(256, 4) void fc_gemm(
        const float* __restrict__ in, const float* __restrict__ w,
        const float* __restrict__ bias, float* __restrict__ out,
        int M, int N, int Kd) {
    constexpr int KC  = 32;
    constexpr int LDA = 68;
    __shared__ float Ash[KC * LDA];
    __shared__ float Bsh[KC * LDA];

    const int tid = threadIdx.x;
    const int n0 = blockIdx.x * 64;

    const int tn = tid & 15;
    const int tm = tid >> 4;

    float acc[4][4] = {{0.f}};

    for (int k0 = 0; k0 < Kd; k0 += KC) {
#pragma unroll
        for (int it = 0; it < 2; ++it) {
            int idx = tid + it * 256;
            int n   = idx >> 3;
            int k4  = idx & 7;
            int k   = k0 + k4 * 4;
            float4 w4 = make_float4(0.f, 0.f, 0.f, 0.f);
            int ng = n0 + n;
            if (ng < N) {
                const float* wp = w + (size_t)ng * Kd + k;
                if (k + 3 < Kd) {
                    w4 = *(const float4*)wp;
                } else {
                    if (k + 0 < Kd) w4.x = wp[0];
                    if (k + 1 < Kd) w4.y = wp[1];
                    if (k + 2 < Kd) w4.z = wp[2];
                    if (k + 3 < Kd) w4.w = wp[3];
                }
            }
            Ash[(k4 * 4 + 0) * LDA + n] = w4.x;
            Ash[(k4 * 4 + 1) * LDA + n] = w4.y;
            Ash[(k4 * 4 + 2) * LDA + n] = w4.z;
            Ash[(k4 * 4 + 3) * LDA + n] = w4.w;
        }
#pragma unroll
        for (int it = 0; it < 2; ++it) {
            int idx = tid + it * 256;
            int m   = idx >> 3;
            int k4  = idx & 7;
            int k   = k0 + k4 * 4;
            float4 x4 = make_float4(0.f, 0.f, 0.f, 0.f);
            if (m < M) {
                const float* xp = in + (size_t)m * Kd + k;
                if (k + 3 < Kd) {
                    x4 = *(const float4*)xp;
                } else {
                    if (k + 0 < Kd) x4.x = xp[0];
                    if (k + 1 < Kd) x4.y = xp[1];
                    if (k + 2 < Kd) x4.z = xp[2];
                    if (k + 3 < Kd) x4.w = xp[3];
                }
            }
            Bsh[(k4 * 4 + 0) * LDA + m] = x4.x;
            Bsh[(k4 * 4 + 1) * LDA + m] = x4.y;
            Bsh[(k4 * 4 + 2) * LDA + m] = x4.z;
            Bsh[(k4 * 4 + 3) * LDA + m] = x4.w;
        }
        __syncthreads();
#pragma unroll
        for (int kk = 0; kk < KC; ++kk) {
            float4 a4 = *(const float4*)&Ash[kk * LDA + tn * 4];
            float4 b4 = *(const float4*)&Bsh[kk * LDA + tm * 4];
            float av[4] = {a4.x, a4.y, a4.z, a4.w};
            float bv[4] = {b4.x, b4.y, b4.z, b4.w};
#pragma unroll
            for (int i = 0; i < 4; ++i)
#pragma unroll
                for (int j = 0; j < 4; ++j)
                    acc[i][j] = fmaf(av[i], bv[j], acc[i][j]);
        }
        __syncthreads();
    }

#pragma unroll
    for (int i = 0; i < 4; ++i) {
        int ng = n0 + tn * 4 + i;
        if (ng >= N) continue;
        float bs = bias[ng];
#pragma unroll
        for (int j = 0; j < 4; ++j) {
            int m = tm * 4 + j;
            if (m >= M) continue;
            float vv = acc[i][j] + bs;
            if (RELU) vv = fmaxf(vv, 0.f);
            out[(size_t)m * N + ng] = vv;
        }
    }
}

// ---------------- maxpool ---------------------------------------------------
__global__ void maxpool_k(const float* __restrict__ in, float* __restrict__ out,
                          int BC, int HIN, int WIN, int HOUT, int WOUT,
                          int KS, int S, int P) {
    int idx = blockIdx.x * blockDim.x + threadIdx.x;
    int total = BC * HOUT * WOUT;
    if (idx >= total) return;
    int wo = idx % WOUT;
    int ho = (idx / WOUT) % HOUT;
    int bc = idx / (WOUT * HOUT);
    int h0 = ho * S - P, w0 = wo * S - P;
    int h1 = h0 + KS, w1 = w0 + KS;
    if (h0 < 0) h0 = 0;
    if (w0 < 0) w0 = 0;
    if (h1 > HIN) h1 = HIN;
    if (w1 > WIN) w1 = WIN;
    const float* base = in + (size_t)bc * HIN * WIN;
    float m = -INFINITY;
    for (int h = h0; h < h1; h++)
        for (int w = w0; w < w1; w++)
            m = fmaxf(m, base[h * WIN + w]);
    out[idx] = m;
}

// ---------------- squash over trailing dim of 8 ----------------------------
__global__ void squash_u(const float* __restrict__ p, float* __restrict__ u, int ncaps) {
    int idx = blockIdx.x * blockDim.x + threadIdx.x;
    if (idx >= ncaps) return;
    const float4* pp = (const float4*)(p + (size_t)idx * 8);
    float4 a = pp[0], b = pp[1];
    float sq = a.x*a.x + a.y*a.y + a.z*a.z + a.w*a.w
             + b.x*b.x + b.y*b.y + b.z*b.z + b.w*b.w;
    float scale = (sq / (1.f + sq)) / sqrtf(sq + 1e-8f);
    float4* uu = (float4*)(u + (size_t)idx * 8);
    float4 oa, ob;
    oa.x = a.x*scale; oa.y = a.y*scale; oa.z = a.z*scale; oa.w = a.w*scale;
    ob.x = b.x*scale; ob.y = b.y*scale; ob.z = b.z*scale; ob.w = b.w*scale;
    uu[0] = oa; uu[1] = ob;
}

// ---------------- softmax over J (axis=1 of [B,J,I]) -----------------------
__global__ void softmax_j(const float* __restrict__ blog, float* __restrict__ c,
                          int Bn, int J, int I) {
    int idx = blockIdx.x * blockDim.x + threadIdx.x;
    if (idx >= Bn * I) return;
    int b = idx / I, i = idx - b * I;
    const float* base = blog + (size_t)b * J * I + i;
    float m = -INFINITY;
    for (int j = 0; j < J; j++) m = fmaxf(m, base[(size_t)j * I]);
    float* cb = c + (size_t)b * J * I + i;
    float sum = 0.f;
    for (int j = 0; j < J; j++) {
        float e = expf(base[(size_t)j * I] - m);
        sum += e;
        cb[(size_t)j * I] = e;
    }
    float inv = 1.f / sum;
    for (int j = 0; j < J; j++) cb[(size_t)j * I] *= inv;
}

// ===========================================================================
// Routing, LDS-staged-W version. Block = (i-chunk of 64, j). W[j, i0:i0+64]
// (32 KB) staged to LDS once, then reused across all 64 batches (4 b/thread).
// ===========================================================================

__device__ __forceinline__ void stage_W(const float* __restrict__ W,
                                        float* __restrict__ wsh,
                                        int j, int i0, int tid) {
    const float4* Wp = (const float4*)(W + ((size_t)j * NI + i0) * 128);
#pragma unroll
    for (int p = 0; p < 8; ++p) {
        int vi  = p * 256 + tid;     // 0..2047 float4s
        int row = vi >> 5;           // 32 float4 per 128-float row
        int c4  = vi & 31;
        float4 f = Wp[vi];
        *(float4*)&wsh[row * LDW + c4 * 4] = f;
    }
}

// partial s: ppart[ic][b*NJ+j][16] = sum_{i in chunk} c[b,j,i] * (W[j,i]@u[b,i])
__global__ __launch_bounds__(256) void route_s_w(
        const float* __restrict__ c, const float* __restrict__ u,
        const float* __restrict__ W, float* __restrict__ ppart, int uniform) {
    __shared__ float wsh[IC * LDW];     // 33.8 KB
    const int tid = threadIdx.x;
    const int icb = blockIdx.x;
    const int j   = blockIdx.y;
    const int i0  = icb * IC;

    stage_W(W, wsh, j, i0, tid);
    __syncthreads();

    const int bg = tid >> 4;            // 0..15 -> batches 4*bg..4*bg+3
    const int iq = tid & 15;            // i = i0 + iq + 16k
    const float invJ = 1.f / (float)NJ;

    float s[4][16];
#pragma unroll
    for (int bb = 0; bb < 4; ++bb)
#pragma unroll
        for (int o = 0; o < 16; ++o) s[bb][o] = 0.f;

#pragma unroll
    for (int k = 0; k < 4; ++k) {
        int il = iq + 16 * k;
        int ig = i0 + il;
        const float* wr = &wsh[il * LDW];
        float4 ua[4], ub[4];
        float cc[4];
#pragma unroll
        for (int bb = 0; bb < 4; ++bb) {
            int b = bg * 4 + bb;
            const float4* up = (const float4*)(u + ((size_t)b * NI + ig) * 8);
            ua[bb] = up[0];
            ub[bb] = up[1];
            cc[bb] = uniform ? invJ : c[((size_t)b * NJ + j) * NI + ig];
        }
#pragma unroll
        for (int o = 0; o < 16; ++o) {
            float4 w0 = *(const float4*)&wr[o * 8];
            float4 w1 = *(const float4*)&wr[o * 8 + 4];
#pragma unroll
            for (int bb = 0; bb < 4; ++bb) {
                float dot = w0.x*ua[bb].x + w0.y*ua[bb].y + w0.z*ua[bb].z + w0.w*ua[bb].w
                          + w1.x*ub[bb].x + w1.y*ub[bb].y + w1.z*ub[bb].z + w1.w*ub[bb].w;
                s[bb][o] = fmaf(cc[bb], dot, s[bb][o]);
            }
        }
    }

    // reduce over the 16 iq-lanes (consecutive within the wave)
#pragma unroll
    for (int off = 8; off > 0; off >>= 1)
#pragma unroll
        for (int bb = 0; bb < 4; ++bb)
#pragma unroll
            for (int o = 0; o < 16; ++o)
                s[bb][o] += __shfl_down(s[bb][o], off, 16);

    if (iq == 0) {
#pragma unroll
        for (int bb = 0; bb < 4; ++bb) {
            int b = bg * 4 + bb;
            size_t base = ((size_t)icb * BJ + (size_t)b * NJ + j) * 16;
#pragma unroll
            for (int o4 = 0; o4 < 4; ++o4)
                *(float4*)&ppart[base + o4 * 4] =
                    make_float4(s[bb][o4*4+0], s[bb][o4*4+1], s[bb][o4*4+2], s[bb][o4*4+3]);
        }
    }
}

// v[bj][16] = squash( sum_ic ppart[ic][bj][16] ).  64 thr = 4 bj x 16 o.
__global__ __launch_bounds__(64) void reduce_squash(
        const float* __restrict__ ppart, float* __restrict__ v) {
    int l = threadIdx.x >> 4;
    int o = threadIdx.x & 15;
    int bj = blockIdx.x * 4 + l;
    float s = 0.f;
    for (int ic = 0; ic < NIC; ic++)
        s += ppart[((size_t)ic * BJ + bj) * 16 + o];
    __shared__ float sarr[4][16];
    sarr[l][o] = s;
    __syncthreads();
    float ssq = 0.f;
#pragma unroll
    for (int k = 0; k < 16; k++) { float t = sarr[l][k]; ssq += t * t; }
    float scale = (ssq / (1.f + ssq)) / sqrtf(ssq + 1e-8f);
    v[(size_t)bj * 16 + o] = s * scale;
}

// blog[b,j,i] (+)= v[b,j,:] . (W[j,i] @ u[b,i])
__global__ __launch_bounds__(256) void route_bupd_w(
        const float* __restrict__ u, const float* __restrict__ W,
        const float* __restrict__ v, float* __restrict__ blog, int accumulate) {
    __shared__ float wsh[IC * LDW];
    const int tid = threadIdx.x;
    const int icb = blockIdx.x;
    const int j   = blockIdx.y;
    const int i0  = icb * IC;

    stage_W(W, wsh, j, i0, tid);
    __syncthreads();

    const int bg = tid >> 4;
    const int iq = tid & 15;

    float vv[4][16];
#pragma unroll
    for (int bb = 0; bb < 4; ++bb) {
        int b = bg * 4 + bb;
        const float4* vp = (const float4*)(v + ((size_t)b * NJ + j) * 16);
#pragma unroll
        for (int o4 = 0; o4 < 4; ++o4) {
            float4 f = vp[o4];
            vv[bb][o4*4+0] = f.x; vv[bb][o4*4+1] = f.y;
            vv[bb][o4*4+2] = f.z; vv[bb][o4*4+3] = f.w;
        }
    }

#pragma unroll
    for (int k = 0; k < 4; ++k) {
        int il = iq + 16 * k;
        int ig = i0 + il;
        const float* wr = &wsh[il * LDW];
        float4 ua[4], ub[4];
#pragma unroll
        for (int bb = 0; bb < 4; ++bb) {
            int b = bg * 4 + bb;
            const float4* up = (const float4*)(u + ((size_t)b * NI + ig) * 8);
            ua[bb] = up[0];
            ub[bb] = up[1];
        }
        float acc[4] = {0.f, 0.f, 0.f, 0.f};
#pragma unroll
        for (int o = 0; o < 16; ++o) {
            float4 w0 = *(const float4*)&wr[o * 8];
            float4 w1 = *(const float4*)&wr[o * 8 + 4];
#pragma unroll
            for (int bb = 0; bb < 4; ++bb) {
                float dot = w0.x*ua[bb].x + w0.y*ua[bb].y + w0.z*ua[bb].z + w0.w*ua[bb].w
                          + w1.x*ub[bb].x + w1.y*ub[bb].y + w1.z*ub[bb].z + w1.w*ub[bb].w;
                acc[bb] = fmaf(vv[bb][o], dot, acc[bb]);
            }
        }
#pragma unroll
        for (int bb = 0; bb < 4; ++bb) {
            int b = bg * 4 + bb;
            size_t idx = ((size_t)b * NJ + j) * NI + ig;
            blog[idx] = accumulate ? (blog[idx] + acc[bb]) : acc[bb];
        }
    }
}

// ---------------------------------------------------------------------------
extern "C" void kernel_launch(void* const* d_in, const int* in_sizes, int n_in,
                              void* d_out, int out_size, void* d_ws, size_t ws_size,
                              hipStream_t stream) {
    const float* x     = (const float*)d_in[0];
    const float* w1    = (const float*)d_in[1];
    const float* b1    = (const float*)d_in[2];
    const float* w2    = (const float*)d_in[3];
    const float* b2    = (const float*)d_in[4];
    const float* w3    = (const float*)d_in[5];
    const float* b3    = (const float*)d_in[6];
    const float* w4    = (const float*)d_in[7];
    const float* b4    = (const float*)d_in[8];
    const float* w5    = (const float*)d_in[9];
    const float* b5    = (const float*)d_in[10];
    const float* pc_w  = (const float*)d_in[11];
    const float* pc_b  = (const float*)d_in[12];
    const float* capsW = (const float*)d_in[13];
    const float* fc1_w = (const float*)d_in[14];
    const float* fc1_b = (const float*)d_in[15];
    const float* fc2_w = (const float*)d_in[16];
    const float* fc2_b = (const float*)d_in[17];
    const float* fc3_w = (const float*)d_in[18];
    const float* fc3_b = (const float*)d_in[19];
    float* outp = (float*)d_out;

    // ws layout: A (80 MB) | Bb (20 MB) | Dd (4 MB)   -- total 104 MB
    char* ws = (char*)d_ws;
    float* A  = (float*)ws;
    float* Bb = (float*)(ws + ((size_t)80 << 20));
    float* Dd = (float*)(ws + ((size_t)100 << 20));
    float* blog  = A;                        // [64,101,1152] (A free after convs)
    float* csm   = A + 7446528;              // [64,101,1152]
    float* ppart = A + 2 * 7446528;          // [18][6464][16] = 7.1 MB
    float* vcap = Dd;                        // [64,101,16]
    float* f1   = Dd + 131072;
    float* f2   = Dd + 131072 + 262144;

    const int B = BATCH;

    // ---- conv stack ----
    conv_igemm<11, 4, 0, 55, true><<<dim3(48, 2, B), dim3(256), 0, stream>>>(
        x, w1, b1, A, 3, 96, 227, 227, 55);
    maxpool_k<<<dim3(ceil_div(B * 96 * 27 * 27, 256)), dim3(256), 0, stream>>>(
        A, Bb, B * 96, 55, 55, 27, 27, 3, 2, 0);
    conv_igemm<5, 1, 2, 27, true><<<dim3(12, 4, B), dim3(256), 0, stream>>>(
        Bb, w2, b2, A, 96, 256, 27, 27, 27);
    maxpool_k<<<dim3(ceil_div(B * 256 * 14 * 14, 256)), dim3(256), 0, stream>>>(
        A, Bb, B * 256, 27, 27, 14, 14, 3, 2, 1);
    conv_igemm<3, 1, 1, 14, true><<<dim3(4, 6, B), dim3(256), 0, stream>>>(
        Bb, w3, b3, A, 256, 384, 14, 14, 14);
    conv_igemm<3, 1, 1, 14, true><<<dim3(4, 6, B), dim3(256), 0, stream>>>(
        A, w4, b4, Bb, 384, 384, 14, 14, 14);
    conv_igemm<3, 1, 1, 14, true><<<dim3(4, 4, B), dim3(256), 0, stream>>>(
        Bb, w5, b5, A, 384, 256, 14, 14, 14);
    maxpool_k<<<dim3(ceil_div(B * 256 * 6 * 6, 256)), dim3(256), 0, stream>>>(
        A, Bb, B * 256, 14, 14, 6, 6, 3, 2, 0);
    conv_igemm<3, 1, 1, 6, false><<<dim3(1, 4, B), dim3(256), 0, stream>>>(
        Bb, pc_w, pc_b, A, 256, 256, 6, 6, 6);
    squash_u<<<dim3(ceil_div(B * 1152, 256)), dim3(256), 0, stream>>>(A, Bb, B * 1152);
    // u now lives in Bb [64,1152,8]

    // ---- dynamic routing (3 iters), W staged in LDS, read once per kernel ----
    dim3 rgrid(NIC, NJ);
    // r=0 (uniform c; first bupd writes blog, no init needed)
    route_s_w<<<rgrid, dim3(256), 0, stream>>>(csm, Bb, capsW, ppart, 1);
    reduce_squash<<<dim3(BJ / 4), dim3(64), 0, stream>>>(ppart, vcap);
    route_bupd_w<<<rgrid, dim3(256), 0, stream>>>(Bb, capsW, vcap, blog, 0);
    // r=1
    softmax_j<<<dim3(ceil_div(B * NI, 256)), dim3(256), 0, stream>>>(
        blog, csm, B, NJ, NI);
    route_s_w<<<rgrid, dim3(256), 0, stream>>>(csm, Bb, capsW, ppart, 0);
    reduce_squash<<<dim3(BJ / 4), dim3(64), 0, stream>>>(ppart, vcap);
    route_bupd_w<<<rgrid, dim3(256), 0, stream>>>(Bb, capsW, vcap, blog, 1);
    // r=2 (final)
    softmax_j<<<dim3(ceil_div(B * NI, 256)), dim3(256), 0, stream>>>(
        blog, csm, B, NJ, NI);
    route_s_w<<<rgrid, dim3(256), 0, stream>>>(csm, Bb, capsW, ppart, 0);
    reduce_squash<<<dim3(BJ / 4), dim3(64), 0, stream>>>(ppart, vcap);

    // ---- MLP head ----
    fc_gemm<true><<<dim3(64), dim3(256), 0, stream>>>(vcap, fc1_w, fc1_b, f1, B, 4096, 1616);
    fc_gemm<true><<<dim3(64), dim3(256), 0, stream>>>(f1, fc2_w, fc2_b, f2, B, 4096, 4096);
    fc_gemm<false><<<dim3(2), dim3(256), 0, stream>>>(f2, fc3_w, fc3_b, outp, B, 101, 4096);
}